// Round 6
// baseline (5987.049 us; speedup 1.0000x reference)
//
#include <hip/hip_runtime.h>
#include <math.h>

// ConvLSTM encoder, MI355X. R15: back to the proven 512-thread config
// (8 waves, 2/SIMD, 256 unified regs/wave, LDS 115,584 B) — R13/R14 proved
// 3 waves/SIMD needs <=168 unified regs, unreachable for this shape
// (estimates ran 40-60 regs under reality; VGPR pinned 84, GB-scale spills).
// R3 counter arithmetic: ~1.6k cy per K-step for 12 MFMA + 6 loads, with
// ~46 VALU insts/K-step from runtime address math (s/3, s<9 branch, toff,
// clamp ternaries) in the '#pragma unroll 1' loops. Fix: FULLY UNROLL both
// K-loops -> all offsets fold to load immediates, branches fold, SSA lets
// the compiler software-pipeline loads with counted waitcnts. L1 MFMA
// dummy-tile guard removed (compute garbage, skip its write); setprio
// removed (null for lockstep waves).

typedef __bf16 bf16x8 __attribute__((ext_vector_type(8)));
typedef __bf16 bf16x4 __attribute__((ext_vector_type(4)));
typedef float  f32x4  __attribute__((ext_vector_type(4)));

__device__ __forceinline__ float sigm(float x)  { return 1.f / (1.f + __expf(-x)); }
__device__ __forceinline__ float ftanh(float x) { float e = __expf(2.f * x); return 1.f - 2.f / (e + 1.f); }

// ---------------- workspace layout (bytes) ----------------
#define OFF_WP0  ((size_t)0)          // [2][10][4][64][8] bf16 = 81,920
#define OFF_WP1  ((size_t)81920)      // [4][27][4][64][8] bf16 = 442,368
#define OFF_WFC  ((size_t)524288)     // [168][64][64] bf16 = 1,376,256
#define OFF_WCP0 ((size_t)1900544)    // [3][32][168] bf16 = 32,256
#define OFF_WCP1 ((size_t)1932800)    // [3][64][168] bf16 = 64,512
#define WS_NEED  ((size_t)1997312)

#define SH0N 9360    // 9*26*40 bf16 per h0 buffer (ping-pong)
#define SH1N 16848   // 9*26*72 bf16 per h1 buffer (ping-pong)
#define SX2N 5376    // 168*32 bf16 im2col x (k<18 taps + k=18 bias lane)

// ---------------- weight pack kernels (fragment-ordered) ----------------
// wp0f[((chh*10+s)*4+g)*512 + L*8 + e] = W0(n = g*32+chh*16+(L&15),
//   k = s*32+(L>>4)*8+e), K-order: k<32 im2col-x (k<18 real, k==18 bias),
//   k>=32 h-taps.
__global__ void pack_w0(const float* __restrict__ wx0, const float* __restrict__ wh0,
                        const float* __restrict__ bx0, __bf16* __restrict__ dst) {
  int o = blockIdx.x * 256 + threadIdx.x;
  if (o >= 40960) return;
  int e = o & 7, L = (o >> 3) & 63;
  int idx = o >> 9;
  int g = idx & 3, sidx = idx >> 2;
  int s = sidx % 10, chh = sidx / 10;
  int n = g * 32 + chh * 16 + (L & 15);
  int k = s * 32 + (L >> 4) * 8 + e;
  float v = 0.f;
  if (k < 32) {
    if (k < 18) {
      int ky = k / 6, rem = k - ky * 6, kx = rem >> 1, ci = rem & 1;
      v = wx0[(n * 2 + ci) * 9 + ky * 3 + kx];
    } else if (k == 18) {
      v = bx0[n];                      // bias tap: pairs with sx2[pix][18]=1.0
    }
  } else {
    int tk = k - 32, tap = tk >> 5, c = tk & 31;
    v = wh0[(n * 32 + c) * 9 + tap];
  }
  dst[o] = (__bf16)v;
}

// wp1f[((chq*27+s)*4+g)*512 + L*8 + e] = W1(n = g*64+chq*16+(L&15),
//   k = s*32+(L>>4)*8+e), K-order: k<288 x-conv taps, k>=288 h-taps.
__global__ void pack_w1(const float* __restrict__ wx1, const float* __restrict__ wh1,
                        __bf16* __restrict__ dst) {
  int o = blockIdx.x * 256 + threadIdx.x;
  if (o >= 221184) return;
  int e = o & 7, L = (o >> 3) & 63;
  int idx = o >> 9;
  int g = idx & 3, sidx = idx >> 2;
  int s = sidx % 27, chq = sidx / 27;
  int n = g * 64 + chq * 16 + (L & 15);
  int k = s * 32 + (L >> 4) * 8 + e;
  float v;
  if (k < 288) {
    int tap = k >> 5, c = k & 31;
    v = wx1[(n * 32 + c) * 9 + tap];
  } else {
    int tk = k - 288, s2 = tk >> 5, c = tk & 31, tap = s2 >> 1, hf = s2 & 1;
    v = wh1[(n * 64 + hf * 32 + c) * 9 + tap];
  }
  dst[o] = (__bf16)v;
}

// Wfc2[pix][ch][n] bf16 = fc1_w[n][ch*168+pix]
__global__ void pack_wfc(const float* __restrict__ w, __bf16* __restrict__ dst) {
  int o = blockIdx.x * 256 + threadIdx.x;
  if (o >= 168 * 64 * 64) return;
  int pix = o >> 12, ch = (o >> 6) & 63, n = o & 63;
  dst[o] = (__bf16)w[n * 10752 + ch * 168 + pix];
}

// peephole weights -> bf16
__global__ void pack_wc(const float* __restrict__ wc0, const float* __restrict__ wc1,
                        __bf16* __restrict__ d0, __bf16* __restrict__ d1) {
  int o = blockIdx.x * 256 + threadIdx.x;
  if (o < 16128) d0[o] = (__bf16)wc0[o];
  else if (o < 48384) d1[o - 16128] = (__bf16)wc1[o - 16128];
}

// ---------------- the persistent ConvLSTM kernel ----------------
__global__ __launch_bounds__(512, 2) void convlstm_persistent(
    const float* __restrict__ input, const float* __restrict__ x_ex,
    const __bf16* __restrict__ wp0, const __bf16* __restrict__ wp1,
    const __bf16* __restrict__ wfc2,
    const float* __restrict__ bx1,
    const __bf16* __restrict__ wcp0, const __bf16* __restrict__ wcp1,
    const float* __restrict__ fc1b,
    const float* __restrict__ exw, const float* __restrict__ exb,
    float* __restrict__ out)
{
  // LDS: 37,440 + 67,392 + 10,752 = 115,584 B -> 1 block/CU, 8 waves.
  __shared__ __bf16 sh0[2 * SH0N];   // h0 ping-pong, [y][x][40] halo
  __shared__ __bf16 sh1[2 * SH1N];   // h1 ping-pong, [y][x][72] halo
  __shared__ __bf16 sx2[SX2N];       // im2col x [pix][32], k<=18 used

  const int b = blockIdx.x;
  const int t = threadIdx.x;
  const int w = t >> 6, L = t & 63;
  const int lo16 = L & 15, hi4 = L >> 4;

  // ---- zero LDS ----
  {
    int* p0 = (int*)sh0;
    for (int i = t; i < SH0N; i += 512) p0[i] = 0;
    int* p1 = (int*)sh1;
    for (int i = t; i < SH1N; i += 512) p1[i] = 0;
    int* p2 = (int*)sx2;
    for (int i = t; i < SX2N / 2; i += 512) p2[i] = 0;
  }
  __syncthreads();

  // ---- build im2col x2 (time-constant), [pix][32], k = ky*6+kx*2+cin ----
  if (t < 168) {
    int iy = t / 24, ix = t - iy * 24;
    __bf16* dst = sx2 + t * 32;
    for (int ky = 0; ky < 3; ++ky) {
      int y = iy + ky - 1;
      if (y < 0 || y >= 7) continue;
      for (int kx = 0; kx < 3; ++kx) {
        int x = ix + kx - 1;
        if (x < 0 || x >= 24) continue;
        int k0 = ky * 6 + kx * 2;
        dst[k0 + 0] = (__bf16)input[((b * 2 + 0) * 7 + y) * 24 + x];
        dst[k0 + 1] = (__bf16)input[((b * 2 + 1) * 7 + y) * 24 + x];
      }
    }
    dst[18] = (__bf16)1.0f;          // bias lane (pairs with wp0 k==18 = bx0)
  }

  // ---- wave roles ----
  // L0: 8 waves = (m3 in 0..3: 3 M-tiles each) x (chh in 0..1 ch-half)
  // L1: 8 waves = (m2 in 0..1: 6 M-tiles, 2 passes of 3) x (chq in 0..3)
  const int chh = w & 1, m3 = w >> 1;
  const int chq = w & 3, m2 = w >> 2;
  const int ch0 = chh * 16 + lo16;     // layer-0 channel (0..31)
  const int ch1 = chq * 16 + lo16;     // layer-1 channel (0..63)

  const __bf16* w0f = wp0 + chh * 20480 + L * 8;   // + (s*4+g)*512
  const __bf16* w1f = wp1 + chq * 55296 + L * 8;   // + (s*4+g)*512

  const float bi1 = bx1[ch1], bf1 = bx1[64 + ch1];
  const float bg1 = bx1[128 + ch1], bo1 = bx1[192 + ch1];

  float c0r[3][4];                     // layer-0 cell state (12 f32/lane)
#pragma unroll
  for (int j = 0; j < 3; ++j)
#pragma unroll
    for (int r = 0; r < 4; ++r) c0r[j][r] = 0.f;

  float c1rA[3][4], c1rB[3][4];        // layer-1 cell state, per pass (24 f32)
#pragma unroll
  for (int j = 0; j < 3; ++j)
#pragma unroll
    for (int r = 0; r < 4; ++r) { c1rA[j][r] = 0.f; c1rB[j][r] = 0.f; }

  __syncthreads();   // x2 + zeroed state visible

#pragma unroll 1
  for (int st = 0; st < 7; ++st) {
    const __bf16* h0r = sh0 + (st & 1) * SH0N;
    __bf16*       h0w = sh0 + ((st + 1) & 1) * SH0N;
    const __bf16* h1r = sh1 + (st & 1) * SH1N;
    __bf16*       h1w = sh1 + ((st + 1) & 1) * SH1N;

    // ======= layer 0: 3 tiles/wave, K fully unrolled (offsets fold) =======
    {
      int b0h[3], b0x[3];
#pragma unroll
      for (int j = 0; j < 3; ++j) {
        int pr = (m3 * 3 + j) * 16 + lo16;
        if (pr > 167) pr = 167;
        int iy = pr / 24, ix = pr - iy * 24;
        b0h[j] = (iy * 26 + ix) * 40;
        b0x[j] = pr * 32 + hi4 * 8;
      }
      f32x4 a0[4][3];
#pragma unroll
      for (int g = 0; g < 4; ++g)
#pragma unroll
        for (int j = 0; j < 3; ++j) a0[g][j] = (f32x4){0.f, 0.f, 0.f, 0.f};

#pragma unroll
      for (int s = 0; s < 10; ++s) {
        bf16x8 af[3], bc[4];
        if (s == 0) {                              // folds per unrolled iter
#pragma unroll
          for (int j = 0; j < 3; ++j) af[j] = *(const bf16x8*)(sx2 + b0x[j]);
        } else {
          int tap = s - 1, ky = tap / 3, kx = tap - ky * 3;   // compile-time
          int toff = (ky * 26 + kx) * 40 + hi4 * 8;
#pragma unroll
          for (int j = 0; j < 3; ++j) af[j] = *(const bf16x8*)(h0r + b0h[j] + toff);
        }
#pragma unroll
        for (int g = 0; g < 4; ++g)
          bc[g] = *(const bf16x8*)(w0f + (s * 4 + g) * 512);
#pragma unroll
        for (int j = 0; j < 3; ++j)
#pragma unroll
          for (int g = 0; g < 4; ++g)
            a0[g][j] = __builtin_amdgcn_mfma_f32_16x16x32_bf16(af[j], bc[g], a0[g][j], 0, 0, 0);
      }

      // epilogue: lane owns (pix = (m3*3+j)*16 + hi4*4 + r, ch0)
#pragma unroll
      for (int j = 0; j < 3; ++j) {
        int p0 = (m3 * 3 + j) * 16 + hi4 * 4;
        if (p0 < 168) {
          const __bf16* wpp = wcp0 + ch0 * 168 + p0;
          bf16x4 w_i = *(const bf16x4*)(wpp);
          bf16x4 w_f = *(const bf16x4*)(wpp + 5376);
          bf16x4 w_o = *(const bf16x4*)(wpp + 10752);
#pragma unroll
          for (int r = 0; r < 4; ++r) {
            int p = p0 + r;
            float c = c0r[j][r];
            float gi = a0[0][j][r];              // bias folded into k=18 tap
            float gf = a0[1][j][r];
            float gc = a0[2][j][r];
            float go = a0[3][j][r];
            float ig = sigm(gi + c * (float)w_i[r]);
            float fg = sigm(gf + c * (float)w_f[r]);
            float cn = fg * c + ig * ftanh(gc);
            float og = sigm(go + cn * (float)w_o[r]);
            float hn = og * ftanh(cn);
            c0r[j][r] = cn;
            int iy = p / 24, ix = p - iy * 24;
            h0w[((iy + 1) * 26 + ix + 1) * 40 + ch0] = (__bf16)hn;
          }
        }
      }
    }
    __syncthreads();   // the ONLY per-step barrier.
    // Hazard walk: h0w(t) writes vs L1 reads of h0w -> ordered here.
    // h1w(t-1) writes (prev L1) vs h1r(t) reads -> a wave reaches this
    // barrier only after finishing prev L1 (both passes), so ordered too.
    // Next-step L0 writes sh0[st&1]; concurrent L1(st) reads only
    // sh0[(st+1)&1] and sh1 -> disjoint. No end-of-step barrier needed.

    // ===== layer 1: 2 passes x 3 tiles, K fully unrolled (27 steps) =======
    auto l1pass = [&](int tb, int ntp, float (&c1)[3][4]) {
      int b1h0[3], b1h1[3];
#pragma unroll
      for (int j = 0; j < 3; ++j) {
        int pr = (tb + j) * 16 + lo16;
        if (pr > 167) pr = 167;
        int iy = pr / 24, ix = pr - iy * 24;
        b1h0[j] = (iy * 26 + ix) * 40;
        b1h1[j] = (iy * 26 + ix) * 72;
      }
      f32x4 a1[4][3];
      {
        const float binit[4] = {bi1, bf1, bg1, bo1};   // bias folded into acc
#pragma unroll
        for (int g = 0; g < 4; ++g)
#pragma unroll
          for (int j = 0; j < 3; ++j)
            a1[g][j] = (f32x4){binit[g], binit[g], binit[g], binit[g]};
      }

#pragma unroll
      for (int s = 0; s < 27; ++s) {
        bf16x8 af[3], bc[4];
        if (s < 9) {                               // folds per unrolled iter
          int ky = s / 3, kx = s - ky * 3;         // compile-time
          int toff = (ky * 26 + kx) * 40 + hi4 * 8;
#pragma unroll
          for (int j = 0; j < 3; ++j) af[j] = *(const bf16x8*)(h0w + b1h0[j] + toff);
        } else {
          int t2 = s - 9, tap = t2 >> 1, hf = t2 & 1;
          int ky = tap / 3, kx = tap - ky * 3;     // compile-time
          int toff = (ky * 26 + kx) * 72 + hf * 32 + hi4 * 8;
#pragma unroll
          for (int j = 0; j < 3; ++j) af[j] = *(const bf16x8*)(h1r + b1h1[j] + toff);
        }
#pragma unroll
        for (int g = 0; g < 4; ++g)
          bc[g] = *(const bf16x8*)(w1f + (s * 4 + g) * 512);
        // no dummy-tile guard: tile 11 computes clamped rows, write skipped
#pragma unroll
        for (int j = 0; j < 3; ++j)
#pragma unroll
          for (int g = 0; g < 4; ++g)
            a1[g][j] = __builtin_amdgcn_mfma_f32_16x16x32_bf16(af[j], bc[g], a1[g][j], 0, 0, 0);
      }

      // epilogue: lane owns (pix = (tb+j)*16 + hi4*4 + r, ch1); direct write
#pragma unroll
      for (int j = 0; j < 3; ++j) {
        int p0 = (tb + j) * 16 + hi4 * 4;
        if (j < ntp && p0 < 168) {
          const __bf16* wpp = wcp1 + ch1 * 168 + p0;
          bf16x4 w_i = *(const bf16x4*)(wpp);
          bf16x4 w_f = *(const bf16x4*)(wpp + 10752);
          bf16x4 w_o = *(const bf16x4*)(wpp + 21504);
#pragma unroll
          for (int r = 0; r < 4; ++r) {
            int p = p0 + r;
            float c = c1[j][r];
            float gi = a1[0][j][r];
            float gf = a1[1][j][r];
            float gc = a1[2][j][r];
            float go = a1[3][j][r];
            float ig = sigm(gi + c * (float)w_i[r]);
            float fg = sigm(gf + c * (float)w_f[r]);
            float cn = fg * c + ig * ftanh(gc);
            float og = sigm(go + cn * (float)w_o[r]);
            float hn = og * ftanh(cn);
            c1[j][r] = cn;
            int iy = p / 24, ix = p - iy * 24;
            h1w[((iy + 1) * 26 + ix + 1) * 72 + ch1] = (__bf16)hn;
          }
        }
      }
    };
    l1pass(m2 * 6,     3,                 c1rA);
    l1pass(m2 * 6 + 3, (m2 == 1) ? 2 : 3, c1rB);   // tile 11 dummy
  }
  __syncthreads();     // h1(7) (in sh1 buffer 1) visible before FC reads

  // ================= FC heads (h1 final in sh1 buffer (6+1)&1 = 1) ========
  {
    const __bf16* h1f = sh1 + SH1N;
    const int o = t & 3, pg = t >> 2;    // o: 16 n's (o*16..); pg 0..127
    float part[16];
#pragma unroll
    for (int q = 0; q < 16; ++q) part[q] = 0.f;
#pragma unroll 1
    for (int jj = 0; jj < 2; ++jj) {
      int p = pg + 128 * jj;
      if (p < 168) {
        int iy = p / 24, ix = p - iy * 24;
        const __bf16* hrow = h1f + ((iy + 1) * 26 + ix + 1) * 72;
        const __bf16* wrow = wfc2 + (size_t)p * 4096 + o * 16;
        for (int ch = 0; ch < 64; ++ch) {
          float hv = (float)hrow[ch];
          bf16x8 wv0 = *(const bf16x8*)(wrow + ch * 64);
          bf16x8 wv1 = *(const bf16x8*)(wrow + ch * 64 + 8);
#pragma unroll
          for (int q = 0; q < 8; ++q) {
            part[q] += hv * (float)wv0[q];
            part[8 + q] += hv * (float)wv1[q];
          }
        }
      }
    }
    float* sacc = (float*)sh0;   // sh0 dead after last step; 32 KB needed
#pragma unroll
    for (int q = 0; q < 16; ++q) sacc[pg * 64 + o * 16 + q] = part[q];
    __syncthreads();
    if (t < 64) {
      float s = fc1b[t];
      for (int pg2 = 0; pg2 < 128; ++pg2) s += sacc[pg2 * 64 + t];
      out[(size_t)b * 128 + t] = fmaxf(s, 0.f);
    } else if (t < 128) {
      int j = t - 64;
      float s = exb[j];
      for (int k = 0; k < 24; ++k) s += x_ex[b * 24 + k] * exw[j * 24 + k];
      out[(size_t)b * 128 + 64 + j] = fmaxf(s, 0.f);
    }
  }
}

// ---------------- launcher ----------------
extern "C" void kernel_launch(void* const* d_in, const int* in_sizes, int n_in,
                              void* d_out, int out_size, void* d_ws, size_t ws_size,
                              hipStream_t stream) {
  const float* input = (const float*)d_in[0];
  const float* x_ex  = (const float*)d_in[1];
  const float* Wx0   = (const float*)d_in[2];
  const float* bx0   = (const float*)d_in[3];
  const float* Wh0   = (const float*)d_in[4];
  const float* Wc0   = (const float*)d_in[5];
  const float* Wx1   = (const float*)d_in[6];
  const float* bx1   = (const float*)d_in[7];
  const float* Wh1   = (const float*)d_in[8];
  const float* Wc1   = (const float*)d_in[9];
  const float* fc1w  = (const float*)d_in[10];
  const float* fc1b  = (const float*)d_in[11];
  const float* exw   = (const float*)d_in[12];
  const float* exb   = (const float*)d_in[13];
  (void)in_sizes; (void)n_in;

  if (ws_size < WS_NEED) {
    hipMemsetAsync(d_out, 0, (size_t)out_size * 4, stream);
    return;
  }

  char* ws = (char*)d_ws;
  __bf16* wp0  = (__bf16*)(ws + OFF_WP0);
  __bf16* wp1  = (__bf16*)(ws + OFF_WP1);
  __bf16* wfc2 = (__bf16*)(ws + OFF_WFC);
  __bf16* wcp0 = (__bf16*)(ws + OFF_WCP0);
  __bf16* wcp1 = (__bf16*)(ws + OFF_WCP1);

  pack_w0<<<160, 256, 0, stream>>>(Wx0, Wh0, bx0, wp0);
  pack_w1<<<864, 256, 0, stream>>>(Wx1, Wh1, wp1);
  pack_wfc<<<2688, 256, 0, stream>>>(fc1w, wfc2);
  pack_wc<<<189, 256, 0, stream>>>(Wc0, Wc1, wcp0, wcp1);

  convlstm_persistent<<<2048, 512, 0, stream>>>(
      input, x_ex, wp0, wp1, wfc2, bx1, wcp0, wcp1, fc1b, exw, exb,
      (float*)d_out);
}

// Round 7
// 2060.264 us; speedup vs baseline: 2.9060x; 2.9060x over previous
//
#include <hip/hip_runtime.h>
#include <math.h>

// ConvLSTM encoder, MI355X. R16: de-spill the proven R3 structure (512 thr,
// 8 waves, 1 block/CU, 2 waves/SIMD, 2456us steady). Evidence: allocator
// pins VGPR_Count per launch_bounds (240@R0-(256,2), 128@(512,2), 84@(768,3))
// and spills whatever exceeds the pin (R3: ~73 f32/lane -> 0.3 GB scratch
// writes). Fixes: (a) __launch_bounds__(512) with NO min-occupancy arg —
// HW already caps at 256 regs (8-wave block = 2 waves/SIMD mandatory), so
// this only removes the artificial pin; (b) c1 cell state -> LDS
// ([168][66] f32, 44.4 KB, padded stride: 2-way conflicts = free), freeing
// 24 persistent arch regs/lane. LDS total 159,936 B <= 160 KiB, still
// 1 block/CU -> occupancy unchanged. K-loops stay rolled with unroll-2
// ping-pong (R6 proved full unroll -> SSA explosion -> 13 GB spill reload).

typedef __bf16 bf16x8 __attribute__((ext_vector_type(8)));
typedef __bf16 bf16x4 __attribute__((ext_vector_type(4)));
typedef float  f32x4  __attribute__((ext_vector_type(4)));

__device__ __forceinline__ float sigm(float x)  { return 1.f / (1.f + __expf(-x)); }
__device__ __forceinline__ float ftanh(float x) { float e = __expf(2.f * x); return 1.f - 2.f / (e + 1.f); }

// ---------------- workspace layout (bytes) ----------------
#define OFF_WP0  ((size_t)0)          // [2][10][4][64][8] bf16 = 81,920
#define OFF_WP1  ((size_t)81920)      // [4][27][4][64][8] bf16 = 442,368
#define OFF_WFC  ((size_t)524288)     // [168][64][64] bf16 = 1,376,256
#define OFF_WCP0 ((size_t)1900544)    // [3][32][168] bf16 = 32,256
#define OFF_WCP1 ((size_t)1932800)    // [3][64][168] bf16 = 64,512
#define WS_NEED  ((size_t)1997312)

#define SH0N 9360    // 9*26*40 bf16 per h0 buffer (ping-pong)
#define SH1N 16848   // 9*26*72 bf16 per h1 buffer (ping-pong)
#define SX2N 5376    // 168*32 bf16 im2col x (k<18 taps + k=18 bias lane)
#define C1LN (168*66) // c1 state fp32, padded stride 66

// ---------------- weight pack kernels (fragment-ordered) ----------------
// wp0f[((chh*10+s)*4+g)*512 + L*8 + e] = W0(n = g*32+chh*16+(L&15),
//   k = s*32+(L>>4)*8+e), K-order: k<32 im2col-x (k<18 real, k==18 bias),
//   k>=32 h-taps.
__global__ void pack_w0(const float* __restrict__ wx0, const float* __restrict__ wh0,
                        const float* __restrict__ bx0, __bf16* __restrict__ dst) {
  int o = blockIdx.x * 256 + threadIdx.x;
  if (o >= 40960) return;
  int e = o & 7, L = (o >> 3) & 63;
  int idx = o >> 9;
  int g = idx & 3, sidx = idx >> 2;
  int s = sidx % 10, chh = sidx / 10;
  int n = g * 32 + chh * 16 + (L & 15);
  int k = s * 32 + (L >> 4) * 8 + e;
  float v = 0.f;
  if (k < 32) {
    if (k < 18) {
      int ky = k / 6, rem = k - ky * 6, kx = rem >> 1, ci = rem & 1;
      v = wx0[(n * 2 + ci) * 9 + ky * 3 + kx];
    } else if (k == 18) {
      v = bx0[n];                      // bias tap: pairs with sx2[pix][18]=1.0
    }
  } else {
    int tk = k - 32, tap = tk >> 5, c = tk & 31;
    v = wh0[(n * 32 + c) * 9 + tap];
  }
  dst[o] = (__bf16)v;
}

// wp1f[((chq*27+s)*4+g)*512 + L*8 + e] = W1(n = g*64+chq*16+(L&15),
//   k = s*32+(L>>4)*8+e), K-order: k<288 x-conv taps, k>=288 h-taps.
__global__ void pack_w1(const float* __restrict__ wx1, const float* __restrict__ wh1,
                        __bf16* __restrict__ dst) {
  int o = blockIdx.x * 256 + threadIdx.x;
  if (o >= 221184) return;
  int e = o & 7, L = (o >> 3) & 63;
  int idx = o >> 9;
  int g = idx & 3, sidx = idx >> 2;
  int s = sidx % 27, chq = sidx / 27;
  int n = g * 64 + chq * 16 + (L & 15);
  int k = s * 32 + (L >> 4) * 8 + e;
  float v;
  if (k < 288) {
    int tap = k >> 5, c = k & 31;
    v = wx1[(n * 32 + c) * 9 + tap];
  } else {
    int tk = k - 288, s2 = tk >> 5, c = tk & 31, tap = s2 >> 1, hf = s2 & 1;
    v = wh1[(n * 64 + hf * 32 + c) * 9 + tap];
  }
  dst[o] = (__bf16)v;
}

// Wfc2[pix][ch][n] bf16 = fc1_w[n][ch*168+pix]
__global__ void pack_wfc(const float* __restrict__ w, __bf16* __restrict__ dst) {
  int o = blockIdx.x * 256 + threadIdx.x;
  if (o >= 168 * 64 * 64) return;
  int pix = o >> 12, ch = (o >> 6) & 63, n = o & 63;
  dst[o] = (__bf16)w[n * 10752 + ch * 168 + pix];
}

// peephole weights -> bf16
__global__ void pack_wc(const float* __restrict__ wc0, const float* __restrict__ wc1,
                        __bf16* __restrict__ d0, __bf16* __restrict__ d1) {
  int o = blockIdx.x * 256 + threadIdx.x;
  if (o < 16128) d0[o] = (__bf16)wc0[o];
  else if (o < 48384) d1[o - 16128] = (__bf16)wc1[o - 16128];
}

// ---------------- the persistent ConvLSTM kernel ----------------
__global__ __launch_bounds__(512) void convlstm_persistent(
    const float* __restrict__ input, const float* __restrict__ x_ex,
    const __bf16* __restrict__ wp0, const __bf16* __restrict__ wp1,
    const __bf16* __restrict__ wfc2,
    const float* __restrict__ bx1,
    const __bf16* __restrict__ wcp0, const __bf16* __restrict__ wcp1,
    const float* __restrict__ fc1b,
    const float* __restrict__ exw, const float* __restrict__ exb,
    float* __restrict__ out)
{
  // LDS: 37,440 + 67,392 + 10,752 + 44,352 = 159,936 B -> 1 block/CU, 8 waves.
  __shared__ __bf16 sh0[2 * SH0N];   // h0 ping-pong, [y][x][40] halo
  __shared__ __bf16 sh1[2 * SH1N];   // h1 ping-pong, [y][x][72] halo
  __shared__ __bf16 sx2[SX2N];       // im2col x [pix][32], k<=18 used
  __shared__ float  c1l[C1LN];       // c1 cell state fp32, [pix][66]

  const int b = blockIdx.x;
  const int t = threadIdx.x;
  const int w = t >> 6, L = t & 63;
  const int lo16 = L & 15, hi4 = L >> 4;

  // ---- zero LDS ----
  {
    int* p0 = (int*)sh0;
    for (int i = t; i < SH0N; i += 512) p0[i] = 0;
    int* p1 = (int*)sh1;
    for (int i = t; i < SH1N; i += 512) p1[i] = 0;
    int* p2 = (int*)sx2;
    for (int i = t; i < SX2N / 2; i += 512) p2[i] = 0;
    for (int i = t; i < C1LN; i += 512) c1l[i] = 0.f;
  }
  __syncthreads();

  // ---- build im2col x2 (time-constant), [pix][32], k = ky*6+kx*2+cin ----
  if (t < 168) {
    int iy = t / 24, ix = t - iy * 24;
    __bf16* dst = sx2 + t * 32;
    for (int ky = 0; ky < 3; ++ky) {
      int y = iy + ky - 1;
      if (y < 0 || y >= 7) continue;
      for (int kx = 0; kx < 3; ++kx) {
        int x = ix + kx - 1;
        if (x < 0 || x >= 24) continue;
        int k0 = ky * 6 + kx * 2;
        dst[k0 + 0] = (__bf16)input[((b * 2 + 0) * 7 + y) * 24 + x];
        dst[k0 + 1] = (__bf16)input[((b * 2 + 1) * 7 + y) * 24 + x];
      }
    }
    dst[18] = (__bf16)1.0f;          // bias lane (pairs with wp0 k==18 = bx0)
  }

  // ---- wave roles ----
  // L0: 8 waves = (m3 in 0..3: 3 M-tiles each) x (chh in 0..1 ch-half)
  // L1: 8 waves = (m2 in 0..1: 6 M-tiles, 2 passes of 3) x (chq in 0..3)
  const int chh = w & 1, m3 = w >> 1;
  const int chq = w & 3, m2 = w >> 2;
  const int ch0 = chh * 16 + lo16;     // layer-0 channel (0..31)
  const int ch1 = chq * 16 + lo16;     // layer-1 channel (0..63)

  const __bf16* w0f = wp0 + chh * 20480 + L * 8;   // + (s*4+g)*512
  const __bf16* w1f = wp1 + chq * 55296 + L * 8;   // + (s*4+g)*512

  const float bi1 = bx1[ch1], bf1 = bx1[64 + ch1];
  const float bg1 = bx1[128 + ch1], bo1 = bx1[192 + ch1];

  float c0r[3][4];                     // layer-0 cell state (12 f32/lane)
#pragma unroll
  for (int j = 0; j < 3; ++j)
#pragma unroll
    for (int r = 0; r < 4; ++r) c0r[j][r] = 0.f;

  __syncthreads();   // x2 + zeroed state visible

#pragma unroll 1
  for (int st = 0; st < 7; ++st) {
    const __bf16* h0r = sh0 + (st & 1) * SH0N;
    __bf16*       h0w = sh0 + ((st + 1) & 1) * SH0N;
    const __bf16* h1r = sh1 + (st & 1) * SH1N;
    __bf16*       h1w = sh1 + ((st + 1) & 1) * SH1N;

    // ================= layer 0: single pass, 3 tiles, unroll-2 =============
    {
      int b0h[3], b0x[3];
#pragma unroll
      for (int j = 0; j < 3; ++j) {
        int pr = (m3 * 3 + j) * 16 + lo16;
        if (pr > 167) pr = 167;
        int iy = pr / 24, ix = pr - iy * 24;
        b0h[j] = (iy * 26 + ix) * 40;
        b0x[j] = pr * 32 + hi4 * 8;
      }
      f32x4 a0[4][3];
#pragma unroll
      for (int g = 0; g < 4; ++g)
#pragma unroll
        for (int j = 0; j < 3; ++j) a0[g][j] = (f32x4){0.f, 0.f, 0.f, 0.f};

      auto loadA0 = [&](int s, bf16x8* af) {
        if (s == 0) {
#pragma unroll
          for (int j = 0; j < 3; ++j) af[j] = *(const bf16x8*)(sx2 + b0x[j]);
        } else {
          int tap = s - 1, ky = tap / 3, kx = tap - ky * 3;
          int toff = (ky * 26 + kx) * 40 + hi4 * 8;
#pragma unroll
          for (int j = 0; j < 3; ++j) af[j] = *(const bf16x8*)(h0r + b0h[j] + toff);
        }
      };
      auto loadB0 = [&](int s, bf16x8* bc) {
#pragma unroll
        for (int g = 0; g < 4; ++g)
          bc[g] = *(const bf16x8*)(w0f + (s * 4 + g) * 512);
      };
      auto mfma0 = [&](bf16x8* af, bf16x8* bc) {
#pragma unroll
        for (int j = 0; j < 3; ++j)
#pragma unroll
          for (int g = 0; g < 4; ++g)
            a0[g][j] = __builtin_amdgcn_mfma_f32_16x16x32_bf16(af[j], bc[g], a0[g][j], 0, 0, 0);
      };

      bf16x8 afA[3], afB[3], bcA[4], bcB[4];
      loadA0(0, afA); loadB0(0, bcA);
      loadA0(1, afB); loadB0(1, bcB);
#pragma unroll 1
      for (int s = 0; s < 10; s += 2) {
        mfma0(afA, bcA);
        int s2 = (s + 2 < 10) ? s + 2 : 9;
        loadA0(s2, afA); loadB0(s2, bcA);
        mfma0(afB, bcB);
        int s3 = (s + 3 < 10) ? s + 3 : 9;
        loadA0(s3, afB); loadB0(s3, bcB);
      }

      // epilogue: lane owns (pix = (m3*3+j)*16 + hi4*4 + r, ch0)
#pragma unroll
      for (int j = 0; j < 3; ++j) {
        int p0 = (m3 * 3 + j) * 16 + hi4 * 4;
        if (p0 < 168) {
          const __bf16* wpp = wcp0 + ch0 * 168 + p0;
          bf16x4 w_i = *(const bf16x4*)(wpp);
          bf16x4 w_f = *(const bf16x4*)(wpp + 5376);
          bf16x4 w_o = *(const bf16x4*)(wpp + 10752);
#pragma unroll
          for (int r = 0; r < 4; ++r) {
            int p = p0 + r;
            float c = c0r[j][r];
            float gi = a0[0][j][r];              // bias folded into k=18 tap
            float gf = a0[1][j][r];
            float gc = a0[2][j][r];
            float go = a0[3][j][r];
            float ig = sigm(gi + c * (float)w_i[r]);
            float fg = sigm(gf + c * (float)w_f[r]);
            float cn = fg * c + ig * ftanh(gc);
            float og = sigm(go + cn * (float)w_o[r]);
            float hn = og * ftanh(cn);
            c0r[j][r] = cn;
            int iy = p / 24, ix = p - iy * 24;
            h0w[((iy + 1) * 26 + ix + 1) * 40 + ch0] = (__bf16)hn;
          }
        }
      }
    }
    __syncthreads();   // the ONLY per-step barrier.
    // Hazard walk: h0w(t) writes vs L1 reads of h0w -> ordered here.
    // h1w(t-1) writes (prev L1) vs h1r(t) reads -> a wave reaches this
    // barrier only after finishing prev L1 (both passes), so ordered too.
    // Next-step L0 writes sh0[st&1]; concurrent L1(st) reads only
    // sh0[(st+1)&1] and sh1 -> disjoint. c1l[(p,ch1)] owned by exactly one
    // lane for all time -> race-free. No end-of-step barrier needed.

    // ======== layer 1: two passes of 3 tiles (c1 state in LDS) ============
    auto l1pass = [&](int tb, int ntp) {
      int b1h0[3], b1h1[3];
#pragma unroll
      for (int j = 0; j < 3; ++j) {
        int pr = (tb + j) * 16 + lo16;
        if (pr > 167) pr = 167;
        int iy = pr / 24, ix = pr - iy * 24;
        b1h0[j] = (iy * 26 + ix) * 40;
        b1h1[j] = (iy * 26 + ix) * 72;
      }
      f32x4 a1[4][3];
      {
        const float binit[4] = {bi1, bf1, bg1, bo1};   // bias folded into acc
#pragma unroll
        for (int g = 0; g < 4; ++g)
#pragma unroll
          for (int j = 0; j < 3; ++j)
            a1[g][j] = (f32x4){binit[g], binit[g], binit[g], binit[g]};
      }

      auto loadA1 = [&](int s, bf16x8* af) {
        if (s < 9) {
          int ky = s / 3, kx = s - ky * 3;
          int toff = (ky * 26 + kx) * 40 + hi4 * 8;
#pragma unroll
          for (int j = 0; j < 3; ++j) af[j] = *(const bf16x8*)(h0w + b1h0[j] + toff);
        } else {
          int t2 = s - 9, tap = t2 >> 1, hf = t2 & 1;
          int ky = tap / 3, kx = tap - ky * 3;
          int toff = (ky * 26 + kx) * 72 + hf * 32 + hi4 * 8;
#pragma unroll
          for (int j = 0; j < 3; ++j) af[j] = *(const bf16x8*)(h1r + b1h1[j] + toff);
        }
      };
      auto loadB1 = [&](int s, bf16x8* bc) {
#pragma unroll
        for (int g = 0; g < 4; ++g)
          bc[g] = *(const bf16x8*)(w1f + (s * 4 + g) * 512);
      };
      auto mfma1 = [&](bf16x8* af, bf16x8* bc) {
#pragma unroll
        for (int j = 0; j < 3; ++j) {
          if (j < ntp) {
#pragma unroll
            for (int g = 0; g < 4; ++g)
              a1[g][j] = __builtin_amdgcn_mfma_f32_16x16x32_bf16(af[j], bc[g], a1[g][j], 0, 0, 0);
          }
        }
      };

      bf16x8 afA[3], afB[3], bcA[4], bcB[4];
      loadA1(0, afA); loadB1(0, bcA);
      loadA1(1, afB); loadB1(1, bcB);
#pragma unroll 1
      for (int s = 0; s < 26; s += 2) {
        mfma1(afA, bcA);
        int s2 = (s + 2 < 27) ? s + 2 : 26;
        loadA1(s2, afA); loadB1(s2, bcA);
        mfma1(afB, bcB);
        int s3 = (s + 3 < 27) ? s + 3 : 26;
        loadA1(s3, afB); loadB1(s3, bcB);
      }
      mfma1(afA, bcA);   // s = 26 tail

      // epilogue: lane owns (pix = (tb+j)*16 + hi4*4 + r, ch1); c1 in LDS
#pragma unroll
      for (int j = 0; j < 3; ++j) {
        int p0 = (tb + j) * 16 + hi4 * 4;
        if (j < ntp && p0 < 168) {
          const __bf16* wpp = wcp1 + ch1 * 168 + p0;
          bf16x4 w_i = *(const bf16x4*)(wpp);
          bf16x4 w_f = *(const bf16x4*)(wpp + 10752);
          bf16x4 w_o = *(const bf16x4*)(wpp + 21504);
#pragma unroll
          for (int r = 0; r < 4; ++r) {
            int p = p0 + r;
            float c = c1l[p * 66 + ch1];
            float gi = a1[0][j][r];
            float gf = a1[1][j][r];
            float gc = a1[2][j][r];
            float go = a1[3][j][r];
            float ig = sigm(gi + c * (float)w_i[r]);
            float fg = sigm(gf + c * (float)w_f[r]);
            float cn = fg * c + ig * ftanh(gc);
            float og = sigm(go + cn * (float)w_o[r]);
            float hn = og * ftanh(cn);
            c1l[p * 66 + ch1] = cn;
            int iy = p / 24, ix = p - iy * 24;
            h1w[((iy + 1) * 26 + ix + 1) * 72 + ch1] = (__bf16)hn;
          }
        }
      }
    };
    l1pass(m2 * 6,     3);
    l1pass(m2 * 6 + 3, (m2 == 1) ? 2 : 3);   // tile 11 dummy
  }
  __syncthreads();     // h1(7) (in sh1 buffer 1) visible before FC reads

  // ================= FC heads (h1 final in sh1 buffer (6+1)&1 = 1) ========
  {
    const __bf16* h1f = sh1 + SH1N;
    const int o = t & 3, pg = t >> 2;    // o: 16 n's (o*16..); pg 0..127
    float part[16];
#pragma unroll
    for (int q = 0; q < 16; ++q) part[q] = 0.f;
#pragma unroll 1
    for (int jj = 0; jj < 2; ++jj) {
      int p = pg + 128 * jj;
      if (p < 168) {
        int iy = p / 24, ix = p - iy * 24;
        const __bf16* hrow = h1f + ((iy + 1) * 26 + ix + 1) * 72;
        const __bf16* wrow = wfc2 + (size_t)p * 4096 + o * 16;
        for (int ch = 0; ch < 64; ++ch) {
          float hv = (float)hrow[ch];
          bf16x8 wv0 = *(const bf16x8*)(wrow + ch * 64);
          bf16x8 wv1 = *(const bf16x8*)(wrow + ch * 64 + 8);
#pragma unroll
          for (int q = 0; q < 8; ++q) {
            part[q] += hv * (float)wv0[q];
            part[8 + q] += hv * (float)wv1[q];
          }
        }
      }
    }
    float* sacc = (float*)sh0;   // sh0 dead after last step; 32 KB needed
#pragma unroll
    for (int q = 0; q < 16; ++q) sacc[pg * 64 + o * 16 + q] = part[q];
    __syncthreads();
    if (t < 64) {
      float s = fc1b[t];
      for (int pg2 = 0; pg2 < 128; ++pg2) s += sacc[pg2 * 64 + t];
      out[(size_t)b * 128 + t] = fmaxf(s, 0.f);
    } else if (t < 128) {
      int j = t - 64;
      float s = exb[j];
      for (int k = 0; k < 24; ++k) s += x_ex[b * 24 + k] * exw[j * 24 + k];
      out[(size_t)b * 128 + 64 + j] = fmaxf(s, 0.f);
    }
  }
}

// ---------------- launcher ----------------
extern "C" void kernel_launch(void* const* d_in, const int* in_sizes, int n_in,
                              void* d_out, int out_size, void* d_ws, size_t ws_size,
                              hipStream_t stream) {
  const float* input = (const float*)d_in[0];
  const float* x_ex  = (const float*)d_in[1];
  const float* Wx0   = (const float*)d_in[2];
  const float* bx0   = (const float*)d_in[3];
  const float* Wh0   = (const float*)d_in[4];
  const float* Wc0   = (const float*)d_in[5];
  const float* Wx1   = (const float*)d_in[6];
  const float* bx1   = (const float*)d_in[7];
  const float* Wh1   = (const float*)d_in[8];
  const float* Wc1   = (const float*)d_in[9];
  const float* fc1w  = (const float*)d_in[10];
  const float* fc1b  = (const float*)d_in[11];
  const float* exw   = (const float*)d_in[12];
  const float* exb   = (const float*)d_in[13];
  (void)in_sizes; (void)n_in;

  if (ws_size < WS_NEED) {
    hipMemsetAsync(d_out, 0, (size_t)out_size * 4, stream);
    return;
  }

  char* ws = (char*)d_ws;
  __bf16* wp0  = (__bf16*)(ws + OFF_WP0);
  __bf16* wp1  = (__bf16*)(ws + OFF_WP1);
  __bf16* wfc2 = (__bf16*)(ws + OFF_WFC);
  __bf16* wcp0 = (__bf16*)(ws + OFF_WCP0);
  __bf16* wcp1 = (__bf16*)(ws + OFF_WCP1);

  pack_w0<<<160, 256, 0, stream>>>(Wx0, Wh0, bx0, wp0);
  pack_w1<<<864, 256, 0, stream>>>(Wx1, Wh1, wp1);
  pack_wfc<<<2688, 256, 0, stream>>>(fc1w, wfc2);
  pack_wc<<<189, 256, 0, stream>>>(Wc0, Wc1, wcp0, wcp1);

  convlstm_persistent<<<2048, 512, 0, stream>>>(
      input, x_ex, wp0, wp1, wfc2, bx1, wcp0, wcp1, fc1b, exw, exb,
      (float*)d_out);
}

// Round 8
// 1813.477 us; speedup vs baseline: 3.3014x; 1.1361x over previous
//
#include <hip/hip_runtime.h>
#include <math.h>

// ConvLSTM encoder, MI355X. R17: VALU-diet on the R7 structure (best: 2060us,
// 512 thr, 8 waves, 1 block/CU, LDS 159,936 B, c1 in LDS). R7 counters:
// VALUBusy 50% INCLUDES MFMA issue (~8% by FLOP math) -> ~23% real VALU +
// ~50% stall; biggest VALU consumer = runtime address math in rolled K-loops
// (tap/3 magic-mul, s<9 select, toff muls, epilogue /24+halo per element).
// Fixes: (1) A-read offsets from __constant__ tables indexed by the
// wave-uniform s -> one s_load per cluster instead of ~15 VALU; L0's s==0
// goes to the prologue (branch-free loop). (2) All step-invariant bases
// (reads incl hi4*8, write bases incl /24+halo — 4-pixel spans never cross
// a row since 24%4==0, c1l bases, peephole rows) hoisted out of the step
// loop. (3) Per-pass LDS pointers; loads select h0w/h1r via one uniform
// cndmask. No structural changes; numerics identical to R7.

typedef __bf16 bf16x8 __attribute__((ext_vector_type(8)));
typedef __bf16 bf16x4 __attribute__((ext_vector_type(4)));
typedef float  f32x4  __attribute__((ext_vector_type(4)));

__device__ __forceinline__ float sigm(float x)  { return 1.f / (1.f + __expf(-x)); }
__device__ __forceinline__ float ftanh(float x) { float e = __expf(2.f * x); return 1.f - 2.f / (e + 1.f); }

// A-read tap offsets (bf16-element units). T0C[s] = toff(tap=s-1), stride-40
// h0 halo rows; T1C[s<9] = stride-40 h0 taps, T1C[s>=9] = stride-72 h1 taps
// with hf*32 folded in.
__device__ __constant__ int T0C[10] = {0, 0, 40, 80, 1040, 1080, 1120, 2080, 2120, 2160};
__device__ __constant__ int T1C[27] = {
    0, 40, 80, 1040, 1080, 1120, 2080, 2120, 2160,
    0, 32, 72, 104, 144, 176, 1872, 1904, 1944, 1976, 2016, 2048,
    3744, 3776, 3816, 3848, 3888, 3920};

// ---------------- workspace layout (bytes) ----------------
#define OFF_WP0  ((size_t)0)          // [2][10][4][64][8] bf16 = 81,920
#define OFF_WP1  ((size_t)81920)      // [4][27][4][64][8] bf16 = 442,368
#define OFF_WFC  ((size_t)524288)     // [168][64][64] bf16 = 1,376,256
#define OFF_WCP0 ((size_t)1900544)    // [3][32][168] bf16 = 32,256
#define OFF_WCP1 ((size_t)1932800)    // [3][64][168] bf16 = 64,512
#define WS_NEED  ((size_t)1997312)

#define SH0N 9360    // 9*26*40 bf16 per h0 buffer (ping-pong)
#define SH1N 16848   // 9*26*72 bf16 per h1 buffer (ping-pong)
#define SX2N 5376    // 168*32 bf16 im2col x (k<18 taps + k=18 bias lane)
#define C1LN (168*66) // c1 state fp32, padded stride 66

// ---------------- weight pack kernels (fragment-ordered) ----------------
__global__ void pack_w0(const float* __restrict__ wx0, const float* __restrict__ wh0,
                        const float* __restrict__ bx0, __bf16* __restrict__ dst) {
  int o = blockIdx.x * 256 + threadIdx.x;
  if (o >= 40960) return;
  int e = o & 7, L = (o >> 3) & 63;
  int idx = o >> 9;
  int g = idx & 3, sidx = idx >> 2;
  int s = sidx % 10, chh = sidx / 10;
  int n = g * 32 + chh * 16 + (L & 15);
  int k = s * 32 + (L >> 4) * 8 + e;
  float v = 0.f;
  if (k < 32) {
    if (k < 18) {
      int ky = k / 6, rem = k - ky * 6, kx = rem >> 1, ci = rem & 1;
      v = wx0[(n * 2 + ci) * 9 + ky * 3 + kx];
    } else if (k == 18) {
      v = bx0[n];                      // bias tap: pairs with sx2[pix][18]=1.0
    }
  } else {
    int tk = k - 32, tap = tk >> 5, c = tk & 31;
    v = wh0[(n * 32 + c) * 9 + tap];
  }
  dst[o] = (__bf16)v;
}

__global__ void pack_w1(const float* __restrict__ wx1, const float* __restrict__ wh1,
                        __bf16* __restrict__ dst) {
  int o = blockIdx.x * 256 + threadIdx.x;
  if (o >= 221184) return;
  int e = o & 7, L = (o >> 3) & 63;
  int idx = o >> 9;
  int g = idx & 3, sidx = idx >> 2;
  int s = sidx % 27, chq = sidx / 27;
  int n = g * 64 + chq * 16 + (L & 15);
  int k = s * 32 + (L >> 4) * 8 + e;
  float v;
  if (k < 288) {
    int tap = k >> 5, c = k & 31;
    v = wx1[(n * 32 + c) * 9 + tap];
  } else {
    int tk = k - 288, s2 = tk >> 5, c = tk & 31, tap = s2 >> 1, hf = s2 & 1;
    v = wh1[(n * 64 + hf * 32 + c) * 9 + tap];
  }
  dst[o] = (__bf16)v;
}

// Wfc2[pix][ch][n] bf16 = fc1_w[n][ch*168+pix]
__global__ void pack_wfc(const float* __restrict__ w, __bf16* __restrict__ dst) {
  int o = blockIdx.x * 256 + threadIdx.x;
  if (o >= 168 * 64 * 64) return;
  int pix = o >> 12, ch = (o >> 6) & 63, n = o & 63;
  dst[o] = (__bf16)w[n * 10752 + ch * 168 + pix];
}

// peephole weights -> bf16
__global__ void pack_wc(const float* __restrict__ wc0, const float* __restrict__ wc1,
                        __bf16* __restrict__ d0, __bf16* __restrict__ d1) {
  int o = blockIdx.x * 256 + threadIdx.x;
  if (o < 16128) d0[o] = (__bf16)wc0[o];
  else if (o < 48384) d1[o - 16128] = (__bf16)wc1[o - 16128];
}

// ---------------- the persistent ConvLSTM kernel ----------------
__global__ __launch_bounds__(512) void convlstm_persistent(
    const float* __restrict__ input, const float* __restrict__ x_ex,
    const __bf16* __restrict__ wp0, const __bf16* __restrict__ wp1,
    const __bf16* __restrict__ wfc2,
    const float* __restrict__ bx1,
    const __bf16* __restrict__ wcp0, const __bf16* __restrict__ wcp1,
    const float* __restrict__ fc1b,
    const float* __restrict__ exw, const float* __restrict__ exb,
    float* __restrict__ out)
{
  // LDS: 37,440 + 67,392 + 10,752 + 44,352 = 159,936 B -> 1 block/CU, 8 waves.
  __shared__ __bf16 sh0[2 * SH0N];   // h0 ping-pong, [y][x][40] halo
  __shared__ __bf16 sh1[2 * SH1N];   // h1 ping-pong, [y][x][72] halo
  __shared__ __bf16 sx2[SX2N];       // im2col x [pix][32], k<=18 used
  __shared__ float  c1l[C1LN];       // c1 cell state fp32, [pix][66]

  const int b = blockIdx.x;
  const int t = threadIdx.x;
  const int w = t >> 6, L = t & 63;
  const int lo16 = L & 15, hi4 = L >> 4;

  // ---- zero LDS ----
  {
    int* p0 = (int*)sh0;
    for (int i = t; i < SH0N; i += 512) p0[i] = 0;
    int* p1 = (int*)sh1;
    for (int i = t; i < SH1N; i += 512) p1[i] = 0;
    int* p2 = (int*)sx2;
    for (int i = t; i < SX2N / 2; i += 512) p2[i] = 0;
    for (int i = t; i < C1LN; i += 512) c1l[i] = 0.f;
  }
  __syncthreads();

  // ---- build im2col x2 (time-constant), [pix][32], k = ky*6+kx*2+cin ----
  if (t < 168) {
    int iy = t / 24, ix = t - iy * 24;
    __bf16* dst = sx2 + t * 32;
    for (int ky = 0; ky < 3; ++ky) {
      int y = iy + ky - 1;
      if (y < 0 || y >= 7) continue;
      for (int kx = 0; kx < 3; ++kx) {
        int x = ix + kx - 1;
        if (x < 0 || x >= 24) continue;
        int k0 = ky * 6 + kx * 2;
        dst[k0 + 0] = (__bf16)input[((b * 2 + 0) * 7 + y) * 24 + x];
        dst[k0 + 1] = (__bf16)input[((b * 2 + 1) * 7 + y) * 24 + x];
      }
    }
    dst[18] = (__bf16)1.0f;          // bias lane (pairs with wp0 k==18 = bx0)
  }

  // ---- wave roles ----
  // L0: 8 waves = (m3 in 0..3: 3 M-tiles each) x (chh in 0..1 ch-half)
  // L1: 8 waves = (m2 in 0..1: 6 M-tiles, 2 passes of 3) x (chq in 0..3)
  const int chh = w & 1, m3 = w >> 1;
  const int chq = w & 3, m2 = w >> 2;
  const int ch0 = chh * 16 + lo16;     // layer-0 channel (0..31)
  const int ch1 = chq * 16 + lo16;     // layer-1 channel (0..63)

  const __bf16* w0f = wp0 + chh * 20480 + L * 8;   // + (s*4+g)*512
  const __bf16* w1f = wp1 + chq * 55296 + L * 8;   // + (s*4+g)*512

  const float bi1 = bx1[ch1], bf1 = bx1[64 + ch1];
  const float bg1 = bx1[128 + ch1], bo1 = bx1[192 + ch1];

  // ---- step-invariant bases (element units; hi4*8 folded into reads,
  //      channel + halo folded into writes; /24 done ONCE here) ----
  int a0h[3], a0x[3], wb0[3];
#pragma unroll
  for (int j = 0; j < 3; ++j) {
    int pr = (m3 * 3 + j) * 16 + lo16;
    if (pr > 167) pr = 167;
    int iy = pr / 24, ix = pr - iy * 24;
    a0h[j] = (iy * 26 + ix) * 40 + hi4 * 8;
    a0x[j] = pr * 32 + hi4 * 8;
    int p0 = (m3 * 3 + j) * 16 + hi4 * 4;   // 4-span never crosses a row
    int py = p0 / 24, px = p0 - py * 24;
    wb0[j] = ((py + 1) * 26 + px + 1) * 40 + ch0;
  }
  int a1hA[3], a1gA[3], wb1A[3], c1bA[3];
  int a1hB[3], a1gB[3], wb1B[3], c1bB[3];
#pragma unroll
  for (int j = 0; j < 3; ++j) {
    {
      int pr = (m2 * 6 + j) * 16 + lo16;
      if (pr > 167) pr = 167;
      int iy = pr / 24, ix = pr - iy * 24;
      a1hA[j] = (iy * 26 + ix) * 40 + hi4 * 8;
      a1gA[j] = (iy * 26 + ix) * 72 + hi4 * 8;
      int p0 = (m2 * 6 + j) * 16 + hi4 * 4;
      int py = p0 / 24, px = p0 - py * 24;
      wb1A[j] = ((py + 1) * 26 + px + 1) * 72 + ch1;
      c1bA[j] = p0 * 66 + ch1;
    }
    {
      int pr = (m2 * 6 + 3 + j) * 16 + lo16;
      if (pr > 167) pr = 167;
      int iy = pr / 24, ix = pr - iy * 24;
      a1hB[j] = (iy * 26 + ix) * 40 + hi4 * 8;
      a1gB[j] = (iy * 26 + ix) * 72 + hi4 * 8;
      int p0 = (m2 * 6 + 3 + j) * 16 + hi4 * 4;
      int py = p0 / 24, px = p0 - py * 24;
      wb1B[j] = ((py + 1) * 26 + px + 1) * 72 + ch1;
      c1bB[j] = p0 * 66 + ch1;
    }
  }
  const __bf16* wcb0 = wcp0 + ch0 * 168;
  const __bf16* wcb1 = wcp1 + ch1 * 168;

  float c0r[3][4];                     // layer-0 cell state (12 f32/lane)
#pragma unroll
  for (int j = 0; j < 3; ++j)
#pragma unroll
    for (int r = 0; r < 4; ++r) c0r[j][r] = 0.f;

  __syncthreads();   // x2 + zeroed state visible

#pragma unroll 1
  for (int st = 0; st < 7; ++st) {
    const __bf16* h0r = sh0 + (st & 1) * SH0N;
    __bf16*       h0w = sh0 + ((st + 1) & 1) * SH0N;
    const __bf16* h1r = sh1 + (st & 1) * SH1N;
    __bf16*       h1w = sh1 + ((st + 1) & 1) * SH1N;

    // ===== layer 0: 3 tiles/wave, unroll-2, table offsets (branch-free) ====
    {
      const __bf16* pH[3];
#pragma unroll
      for (int j = 0; j < 3; ++j) pH[j] = h0r + a0h[j];

      f32x4 a0[4][3];
#pragma unroll
      for (int g = 0; g < 4; ++g)
#pragma unroll
        for (int j = 0; j < 3; ++j) a0[g][j] = (f32x4){0.f, 0.f, 0.f, 0.f};

      auto loadA0h = [&](int s, bf16x8* af) {     // s >= 1 only
        int toff = T0C[s];                        // uniform s -> s_load
#pragma unroll
        for (int j = 0; j < 3; ++j) af[j] = *(const bf16x8*)(pH[j] + toff);
      };
      auto loadB0 = [&](int s, bf16x8* bc) {
#pragma unroll
        for (int g = 0; g < 4; ++g)
          bc[g] = *(const bf16x8*)(w0f + (s * 4 + g) * 512);
      };
      auto mfma0 = [&](bf16x8* af, bf16x8* bc) {
#pragma unroll
        for (int j = 0; j < 3; ++j)
#pragma unroll
          for (int g = 0; g < 4; ++g)
            a0[g][j] = __builtin_amdgcn_mfma_f32_16x16x32_bf16(af[j], bc[g], a0[g][j], 0, 0, 0);
      };

      bf16x8 afA[3], afB[3], bcA[4], bcB[4];
#pragma unroll
      for (int j = 0; j < 3; ++j) afA[j] = *(const bf16x8*)(sx2 + a0x[j]);   // s=0
      loadB0(0, bcA);
      loadA0h(1, afB); loadB0(1, bcB);
#pragma unroll 1
      for (int s = 0; s < 10; s += 2) {
        mfma0(afA, bcA);
        int s2 = (s + 2 < 10) ? s + 2 : 9;
        loadA0h(s2, afA); loadB0(s2, bcA);
        mfma0(afB, bcB);
        int s3 = (s + 3 < 10) ? s + 3 : 9;
        loadA0h(s3, afB); loadB0(s3, bcB);
      }

      // epilogue: precomputed write/peephole bases; stride-40 row walk
#pragma unroll
      for (int j = 0; j < 3; ++j) {
        int p0 = (m3 * 3 + j) * 16 + hi4 * 4;
        if (p0 < 168) {
          const __bf16* wpp = wcb0 + p0;
          bf16x4 w_i = *(const bf16x4*)(wpp);
          bf16x4 w_f = *(const bf16x4*)(wpp + 5376);
          bf16x4 w_o = *(const bf16x4*)(wpp + 10752);
#pragma unroll
          for (int r = 0; r < 4; ++r) {
            float c = c0r[j][r];
            float gi = a0[0][j][r];              // bias folded into k=18 tap
            float gf = a0[1][j][r];
            float gc = a0[2][j][r];
            float go = a0[3][j][r];
            float ig = sigm(gi + c * (float)w_i[r]);
            float fg = sigm(gf + c * (float)w_f[r]);
            float cn = fg * c + ig * ftanh(gc);
            float og = sigm(go + cn * (float)w_o[r]);
            float hn = og * ftanh(cn);
            c0r[j][r] = cn;
            h0w[wb0[j] + r * 40] = (__bf16)hn;
          }
        }
      }
    }
    __syncthreads();   // the ONLY per-step barrier.
    // Hazard walk: h0w(t) writes vs L1 reads of h0w -> ordered here.
    // h1w(t-1) writes (prev L1) vs h1r(t) reads -> a wave reaches this
    // barrier only after finishing prev L1 (both passes), so ordered too.
    // Next-step L0 writes sh0[st&1]; concurrent L1(st) reads only
    // sh0[(st+1)&1] and sh1 -> disjoint. c1l[(p,ch1)] owned by exactly one
    // lane for all time -> race-free. No end-of-step barrier needed.

    // ===== layer 1: two passes of 3 tiles, table offsets + uniform select ==
    auto l1pass = [&](int tb, int ntp, const int (&a1h)[3], const int (&a1g)[3],
                      const int (&wb1)[3], const int (&c1b)[3]) {
      const __bf16* pA[3]; const __bf16* pB[3];
#pragma unroll
      for (int j = 0; j < 3; ++j) { pA[j] = h0w + a1h[j]; pB[j] = h1r + a1g[j]; }

      f32x4 a1[4][3];
      {
        const float binit[4] = {bi1, bf1, bg1, bo1};   // bias folded into acc
#pragma unroll
        for (int g = 0; g < 4; ++g)
#pragma unroll
          for (int j = 0; j < 3; ++j)
            a1[g][j] = (f32x4){binit[g], binit[g], binit[g], binit[g]};
      }

      auto loadA1 = [&](int s, bf16x8* af) {
        int toff = T1C[s];                        // uniform s -> s_load
#pragma unroll
        for (int j = 0; j < 3; ++j) {
          const __bf16* p = (s < 9) ? pA[j] : pB[j];   // uniform cndmask
          af[j] = *(const bf16x8*)(p + toff);
        }
      };
      auto loadB1 = [&](int s, bf16x8* bc) {
#pragma unroll
        for (int g = 0; g < 4; ++g)
          bc[g] = *(const bf16x8*)(w1f + (s * 4 + g) * 512);
      };
      auto mfma1 = [&](bf16x8* af, bf16x8* bc) {
#pragma unroll
        for (int j = 0; j < 3; ++j) {
          if (j < ntp) {
#pragma unroll
            for (int g = 0; g < 4; ++g)
              a1[g][j] = __builtin_amdgcn_mfma_f32_16x16x32_bf16(af[j], bc[g], a1[g][j], 0, 0, 0);
          }
        }
      };

      bf16x8 afA[3], afB[3], bcA[4], bcB[4];
      loadA1(0, afA); loadB1(0, bcA);
      loadA1(1, afB); loadB1(1, bcB);
#pragma unroll 1
      for (int s = 0; s < 26; s += 2) {
        mfma1(afA, bcA);
        int s2 = (s + 2 < 27) ? s + 2 : 26;
        loadA1(s2, afA); loadB1(s2, bcA);
        mfma1(afB, bcB);
        int s3 = (s + 3 < 27) ? s + 3 : 26;
        loadA1(s3, afB); loadB1(s3, bcB);
      }
      mfma1(afA, bcA);   // s = 26 tail

      // epilogue: precomputed bases; strides 72 (h1w) / 66 (c1l)
#pragma unroll
      for (int j = 0; j < 3; ++j) {
        int p0 = (tb + j) * 16 + hi4 * 4;
        if (j < ntp && p0 < 168) {
          const __bf16* wpp = wcb1 + p0;
          bf16x4 w_i = *(const bf16x4*)(wpp);
          bf16x4 w_f = *(const bf16x4*)(wpp + 10752);
          bf16x4 w_o = *(const bf16x4*)(wpp + 21504);
#pragma unroll
          for (int r = 0; r < 4; ++r) {
            float c = c1l[c1b[j] + r * 66];
            float gi = a1[0][j][r];
            float gf = a1[1][j][r];
            float gc = a1[2][j][r];
            float go = a1[3][j][r];
            float ig = sigm(gi + c * (float)w_i[r]);
            float fg = sigm(gf + c * (float)w_f[r]);
            float cn = fg * c + ig * ftanh(gc);
            float og = sigm(go + cn * (float)w_o[r]);
            float hn = og * ftanh(cn);
            c1l[c1b[j] + r * 66] = cn;
            h1w[wb1[j] + r * 72] = (__bf16)hn;
          }
        }
      }
    };
    l1pass(m2 * 6,     3,                 a1hA, a1gA, wb1A, c1bA);
    l1pass(m2 * 6 + 3, (m2 == 1) ? 2 : 3, a1hB, a1gB, wb1B, c1bB);
  }
  __syncthreads();     // h1(7) (in sh1 buffer 1) visible before FC reads

  // ================= FC heads (h1 final in sh1 buffer (6+1)&1 = 1) ========
  {
    const __bf16* h1f = sh1 + SH1N;
    const int o = t & 3, pg = t >> 2;    // o: 16 n's (o*16..); pg 0..127
    float part[16];
#pragma unroll
    for (int q = 0; q < 16; ++q) part[q] = 0.f;
#pragma unroll 1
    for (int jj = 0; jj < 2; ++jj) {
      int p = pg + 128 * jj;
      if (p < 168) {
        int iy = p / 24, ix = p - iy * 24;
        const __bf16* hrow = h1f + ((iy + 1) * 26 + ix + 1) * 72;
        const __bf16* wrow = wfc2 + (size_t)p * 4096 + o * 16;
        for (int ch = 0; ch < 64; ++ch) {
          float hv = (float)hrow[ch];
          bf16x8 wv0 = *(const bf16x8*)(wrow + ch * 64);
          bf16x8 wv1 = *(const bf16x8*)(wrow + ch * 64 + 8);
#pragma unroll
          for (int q = 0; q < 8; ++q) {
            part[q] += hv * (float)wv0[q];
            part[8 + q] += hv * (float)wv1[q];
          }
        }
      }
    }
    float* sacc = (float*)sh0;   // sh0 dead after last step; 32 KB needed
#pragma unroll
    for (int q = 0; q < 16; ++q) sacc[pg * 64 + o * 16 + q] = part[q];
    __syncthreads();
    if (t < 64) {
      float s = fc1b[t];
      for (int pg2 = 0; pg2 < 128; ++pg2) s += sacc[pg2 * 64 + t];
      out[(size_t)b * 128 + t] = fmaxf(s, 0.f);
    } else if (t < 128) {
      int j = t - 64;
      float s = exb[j];
      for (int k = 0; k < 24; ++k) s += x_ex[b * 24 + k] * exw[j * 24 + k];
      out[(size_t)b * 128 + 64 + j] = fmaxf(s, 0.f);
    }
  }
}

// ---------------- launcher ----------------
extern "C" void kernel_launch(void* const* d_in, const int* in_sizes, int n_in,
                              void* d_out, int out_size, void* d_ws, size_t ws_size,
                              hipStream_t stream) {
  const float* input = (const float*)d_in[0];
  const float* x_ex  = (const float*)d_in[1];
  const float* Wx0   = (const float*)d_in[2];
  const float* bx0   = (const float*)d_in[3];
  const float* Wh0   = (const float*)d_in[4];
  const float* Wc0   = (const float*)d_in[5];
  const float* Wx1   = (const float*)d_in[6];
  const float* bx1   = (const float*)d_in[7];
  const float* Wh1   = (const float*)d_in[8];
  const float* Wc1   = (const float*)d_in[9];
  const float* fc1w  = (const float*)d_in[10];
  const float* fc1b  = (const float*)d_in[11];
  const float* exw   = (const float*)d_in[12];
  const float* exb   = (const float*)d_in[13];
  (void)in_sizes; (void)n_in;

  if (ws_size < WS_NEED) {
    hipMemsetAsync(d_out, 0, (size_t)out_size * 4, stream);
    return;
  }

  char* ws = (char*)d_ws;
  __bf16* wp0  = (__bf16*)(ws + OFF_WP0);
  __bf16* wp1  = (__bf16*)(ws + OFF_WP1);
  __bf16* wfc2 = (__bf16*)(ws + OFF_WFC);
  __bf16* wcp0 = (__bf16*)(ws + OFF_WCP0);
  __bf16* wcp1 = (__bf16*)(ws + OFF_WCP1);

  pack_w0<<<160, 256, 0, stream>>>(Wx0, Wh0, bx0, wp0);
  pack_w1<<<864, 256, 0, stream>>>(Wx1, Wh1, wp1);
  pack_wfc<<<2688, 256, 0, stream>>>(fc1w, wfc2);
  pack_wc<<<189, 256, 0, stream>>>(Wc0, Wc1, wcp0, wcp1);

  convlstm_persistent<<<2048, 512, 0, stream>>>(
      input, x_ex, wp0, wp1, wfc2, bx1, wcp0, wcp1, fc1b, exw, exb,
      (float*)d_out);
}